// Round 9
// baseline (476.746 us; speedup 1.0000x reference)
//
#include <hip/hip_runtime.h>

// Problem constants (fixed by setup_inputs)
#define BB 4
#define SS 2048
#define HH 4096
#define KVH 8
#define DD 128
#define MAXSEQ 4096
#define RANK 64
#define HDN 1024   // H/4

typedef float f4 __attribute__((ext_vector_type(4)));

// Workspace layout (float slots):
//   [0, 1048576)       parts[sch][b][c]  (64 * 4 * 4096)
//   [1048576, 1052672) hdn (B*HDN)
//   [1052672, 1052680) strat (B*2)  (16B aligned)
//   ints: 1052680/81/82 = ticket1, ticket2, flag
//   ints at [1052688, 1054736): inv[SS]
#define WS_PARTS 0
#define WS_HDN   1048576
#define WS_STRAT 1052672
#define WS_CTRL  1052680
#define WS_INV   1052688

#define GRID 1024
#define TPB  256

// K0: reset control words (graph-replay-deterministic)
__global__ void reset_kernel(int* __restrict__ ctrl) {
    if (threadIdx.x < 3) ctrl[threadIdx.x] = 0;
}

__global__ __launch_bounds__(TPB, 4)
void mega_kernel(const float* __restrict__ hidden,
                 const float* __restrict__ key,
                 const float* __restrict__ value,
                 const float* __restrict__ k_cache,
                 const float* __restrict__ v_cache,
                 const float* __restrict__ k_left,
                 const float* __restrict__ v_left,
                 const float* __restrict__ w1,
                 const float* __restrict__ b1,
                 const float* __restrict__ w2,
                 const float* __restrict__ b2,
                 const int* __restrict__ cache_position,
                 const int* __restrict__ layer_idx,
                 float* __restrict__ wsf,
                 float* __restrict__ out) {
    const int blk = blockIdx.x, t = threadIdx.x;
    float* parts = wsf + WS_PARTS;
    float* hdn   = wsf + WS_HDN;
    float* strat = wsf + WS_STRAT;
    int* ctrl    = (int*)wsf + WS_CTRL;
    int* inv     = (int*)wsf + WS_INV;
    int* ticket1 = ctrl + 0;
    int* ticket2 = ctrl + 1;
    int* flag    = ctrl + 2;

    // ---------------- Phase A: pool partials + side duties (all blocks) ----
    if (blk >= 1016) {                     // 8 blocks: inv = -1
        inv[(blk - 1016) * 256 + t] = -1;
    } else if (blk >= 1014) {              // 2 blocks: hdn = 0
        int i = (blk - 1014) * 256 + t;
        #pragma unroll
        for (int u = 0; u < 8; ++u) hdn[i * 8 + u] = 0.0f;
    }
    {
        int b    = blk >> 8;
        int sch  = (blk >> 2) & 63;
        int cblk = blk & 3;
        int c0 = cblk * 1024 + t * 4;
        const float* base = hidden + (size_t)b * SS * HH + (size_t)sch * 32 * HH + c0;
        f4 acc = (f4)(0.f);
        #pragma unroll 8
        for (int s = 0; s < 32; ++s)
            acc += *(const f4*)(base + (size_t)s * HH);
        *(f4*)(parts + (size_t)sch * (BB * HH) + b * HH + c0) = acc;
    }
    __threadfence();
    __syncthreads();
    if (t == 0) atomicAdd(ticket1, 1);

    // ---------------- Role phases (block-uniform branches) ------------------
    if (blk < 257) {
        // GEMV: 16 w1-rows per block (block 256: rows 4096..4097)
        if (t == 0) {
            while (__hip_atomic_load(ticket1, __ATOMIC_ACQUIRE,
                                     __HIP_MEMORY_SCOPE_AGENT) < GRID)
                __builtin_amdgcn_s_sleep(8);
        }
        __syncthreads();
        __shared__ float feats_s[16][4];
        const int k0 = blk * 16;
        const int kcnt = (blk < 256) ? 16 : 2;
        if (blk < 256) {
            int kk = t >> 4, bb = (t >> 2) & 3, sub = t & 3;
            const float* src = parts + (size_t)(sub * 16) * (BB * HH) + bb * HH + (k0 + kk);
            float r = 0.f;
            #pragma unroll
            for (int u = 0; u < 16; ++u)
                r += src[(size_t)u * (BB * HH)];
            r += __shfl_xor(r, 1, 64);
            r += __shfl_xor(r, 2, 64);
            if (sub == 0) feats_s[kk][bb] = r * (1.0f / (float)SS);
            __syncthreads();
        }
        int j0 = t * 4;
        f4 acc[BB];
        #pragma unroll
        for (int b = 0; b < BB; ++b) acc[b] = (f4)(0.f);
        for (int kk = 0; kk < kcnt; ++kk) {
            int k = k0 + kk;
            f4 w = *(const f4*)(w1 + (size_t)k * HDN + j0);
            float f[BB];
            if (blk < 256) {
                #pragma unroll
                for (int b = 0; b < BB; ++b) f[b] = feats_s[kk][b];
            } else {
                float v = (kk == 0) ? (float)(*layer_idx) : (float)SS;
                #pragma unroll
                for (int b = 0; b < BB; ++b) f[b] = v;
            }
            #pragma unroll
            for (int b = 0; b < BB; ++b) acc[b] += f[b] * w;
        }
        #pragma unroll
        for (int b = 0; b < BB; ++b) {
            float* h = hdn + b * HDN + j0;
            atomicAdd(h + 0, acc[b].x);
            atomicAdd(h + 1, acc[b].y);
            atomicAdd(h + 2, acc[b].z);
            atomicAdd(h + 3, acc[b].w);
        }
        __threadfence();
        __syncthreads();
        if (t == 0) atomicAdd(ticket2, 1);
    } else if (blk < 265) {
        // scatter-inv (8 blocks)
        if (t == 0) {
            while (__hip_atomic_load(ticket1, __ATOMIC_ACQUIRE,
                                     __HIP_MEMORY_SCOPE_AGENT) < GRID)
                __builtin_amdgcn_s_sleep(8);
        }
        __syncthreads();
        int i = (blk - 257) * 256 + t;
        int pos = cache_position[i];
        if (pos >= 0 && pos < SS) atomicMax(&inv[pos], i);  // last-wins
        __threadfence();
        __syncthreads();
        if (t == 0) atomicAdd(ticket2, 1);
    } else if (blk == 265) {
        // mlp2 producer
        if (t == 0) {
            while (__hip_atomic_load(ticket2, __ATOMIC_ACQUIRE,
                                     __HIP_MEMORY_SCOPE_AGENT) < 265)
                __builtin_amdgcn_s_sleep(8);
        }
        __syncthreads();
        __shared__ float wred[4][16];
        __shared__ float logits[16];
        int j0 = t * 4;
        float l[BB][4];
        #pragma unroll
        for (int b = 0; b < BB; ++b)
            #pragma unroll
            for (int m = 0; m < 4; ++m) l[b][m] = 0.f;
        #pragma unroll
        for (int jj = 0; jj < 4; ++jj) {
            int j = j0 + jj;
            float bias = b1[j];
            f4 w2v = *(const f4*)(w2 + j * 4);
            #pragma unroll
            for (int b = 0; b < BB; ++b) {
                float h = hdn[b * HDN + j] + bias;
                h = h > 0.f ? h : 0.f;
                l[b][0] = fmaf(h, w2v.x, l[b][0]);
                l[b][1] = fmaf(h, w2v.y, l[b][1]);
                l[b][2] = fmaf(h, w2v.z, l[b][2]);
                l[b][3] = fmaf(h, w2v.w, l[b][3]);
            }
        }
        int wave = t >> 6, lane = t & 63;
        #pragma unroll
        for (int off = 32; off > 0; off >>= 1)
            #pragma unroll
            for (int b = 0; b < BB; ++b)
                #pragma unroll
                for (int m = 0; m < 4; ++m)
                    l[b][m] += __shfl_down(l[b][m], off, 64);
        if (lane == 0)
            #pragma unroll
            for (int b = 0; b < BB; ++b)
                #pragma unroll
                for (int m = 0; m < 4; ++m)
                    wred[wave][b * 4 + m] = l[b][m];
        __syncthreads();
        if (t < 16) logits[t] = wred[0][t] + wred[1][t] + wred[2][t] + wred[3][t] + b2[t & 3];
        __syncthreads();
        if (t < BB) {
            float v0 = logits[t * 4 + 0], v1 = logits[t * 4 + 1];
            float v2 = logits[t * 4 + 2], v3 = logits[t * 4 + 3];
            float mx = fmaxf(fmaxf(v0, v1), fmaxf(v2, v3));
            float e0 = __expf(v0 - mx), e1 = __expf(v1 - mx);
            float e2 = __expf(v2 - mx), e3 = __expf(v3 - mx);
            float den = e0 + e1 + e2 + e3;
            strat[t * 2 + 0] = e0 / den;
            strat[t * 2 + 1] = e1 / den;
        }
        __threadfence();
        __syncthreads();
        if (t == 0)
            __hip_atomic_store(flag, 1, __ATOMIC_RELEASE, __HIP_MEMORY_SCOPE_AGENT);
    }

    // ---------------- Out phase (all blocks, gated on flag) -----------------
    if (t == 0) {
        while (__hip_atomic_load(flag, __ATOMIC_ACQUIRE,
                                 __HIP_MEMORY_SCOPE_AGENT) == 0)
            __builtin_amdgcn_s_sleep(8);
    }
    __syncthreads();
    f4 s01 = *(const f4*)(strat);        // b0:w0,wl  b1:w0,wl
    f4 s23 = *(const f4*)(strat + 4);    // b2:w0,wl  b3:w0,wl
    const int KV_OFF = BB * KVH * SS * (DD / 4);   // 2,097,152 f4
    f4* outv = (f4*)out;
    #pragma unroll
    for (int it = 0; it < 8; ++it) {
        int idx = it * (GRID * TPB) + blk * TPB + t;
        int b = it >> 1;                 // == idx >> 19
        float w0 = (b == 0) ? s01.x : (b == 1) ? s01.z : (b == 2) ? s23.x : s23.z;
        float wl = (b == 0) ? s01.y : (b == 1) ? s01.w : (b == 2) ? s23.y : s23.w;
        int d4 = idx & 31;
        int r  = idx >> 5;
        int s  = r & (SS - 1);
        int bh = r >> 11;
        int i = inv[s];
        bool hasLeft = d4 < (RANK / 4);
        f4 kd, vd, kl = (f4)(0.f), vl = (f4)(0.f);
        if (i >= 0) {
            size_t base = ((size_t)bh * SS + i) * DD;
            kd = *((const f4*)(key + base) + d4);
            vd = *((const f4*)(value + base) + d4);
            if (hasLeft) { kl = kd; vl = vd; }
        } else {
            size_t cbase = ((size_t)bh * MAXSEQ + s) * DD;
            kd = *((const f4*)(k_cache + cbase) + d4);
            vd = *((const f4*)(v_cache + cbase) + d4);
            if (hasLeft) {
                size_t lbase = ((size_t)bh * MAXSEQ + s) * RANK;
                kl = *((const f4*)(k_left + lbase) + d4);
                vl = *((const f4*)(v_left + lbase) + d4);
            }
        }
        f4 ko = w0 * kd + wl * kl;
        f4 vo = w0 * vd + wl * vl;
        outv[idx] = ko;
        outv[idx + KV_OFF] = vo;
    }
}

extern "C" void kernel_launch(void* const* d_in, const int* in_sizes, int n_in,
                              void* d_out, int out_size, void* d_ws, size_t ws_size,
                              hipStream_t stream) {
    const float* hidden   = (const float*)d_in[0];
    const float* key      = (const float*)d_in[1];
    const float* value    = (const float*)d_in[2];
    const float* k_cache  = (const float*)d_in[3];
    const float* v_cache  = (const float*)d_in[4];
    const float* k_left   = (const float*)d_in[5];
    const float* v_left   = (const float*)d_in[6];
    const float* w1       = (const float*)d_in[7];
    const float* b1       = (const float*)d_in[8];
    const float* w2       = (const float*)d_in[9];
    const float* b2       = (const float*)d_in[10];
    const int*   cachepos = (const int*)d_in[11];
    const int*   layeridx = (const int*)d_in[12];
    float* out = (float*)d_out;
    float* wsf = (float*)d_ws;
    int*   ctrl = (int*)wsf + WS_CTRL;

    // K0: reset tickets/flag (must be deterministic per call)
    reset_kernel<<<1, 64, 0, stream>>>(ctrl);
    // K1: fused pool -> GEMV -> mlp2 -> out, ticket/flag-ordered
    mega_kernel<<<GRID, TPB, 0, stream>>>(
        hidden, key, value, k_cache, v_cache, k_left, v_left,
        w1, b1, w2, b2, cachepos, layeridx, wsf, out);
}

// Round 10
// 86.913 us; speedup vs baseline: 5.4853x; 5.4853x over previous
//
#include <hip/hip_runtime.h>

// Problem constants (fixed by setup_inputs)
#define BB 4
#define SS 2048
#define HH 4096
#define KVH 8
#define DD 128
#define MAXSEQ 4096
#define RANK 64
#define HDN 1024   // H/4
#define NSCH 128   // s-chunks for pool partials (16 rows each)

typedef float f4 __attribute__((ext_vector_type(4)));

// Workspace layout (float slots):
//   [0, 2097152)            parts[sch][b][c]  (128 * 4 * 4096)
//   [2097152, 2101248)      hdn (B*HDN)
//   ints at [2101248, 2103296): inv[SS]
#define WS_PARTS 0
#define WS_HDN   2097152
#define WS_INV   2101248

// ---------------- K1: pool partials (no atomics, nt stores) ----------------
// grid = 2048 blocks x 256. Block: b(4) x sch(128) x cblk(4); 16 rows x 1024 ch.
__global__ void pool_kernel(const float* __restrict__ hidden,
                            float* __restrict__ parts,
                            float* __restrict__ hdn,
                            int* __restrict__ inv) {
    const int blk = blockIdx.x, t = threadIdx.x;
    // side duties (these blocks also do pool work below)
    if (blk >= 2040) {                     // 8 blocks: inv = -1
        inv[(blk - 2040) * 256 + t] = -1;
    } else if (blk >= 2038) {              // 2 blocks: hdn = 0 (4096 floats)
        int i = (blk - 2038) * 256 + t;
        #pragma unroll
        for (int u = 0; u < 8; ++u) hdn[i * 8 + u] = 0.0f;
    }
    int b    = blk >> 9;
    int sch  = (blk >> 2) & 127;
    int cblk = blk & 3;
    int c0 = cblk * 1024 + t * 4;
    const float* base = hidden + (size_t)b * SS * HH + (size_t)sch * 16 * HH + c0;
    f4 acc = (f4)(0.f);
    #pragma unroll
    for (int s = 0; s < 16; ++s)
        acc += *(const f4*)(base + (size_t)s * HH);
    // parts[sch][b][c0..c0+3] — contiguous nt f4 store (single-use scratch)
    __builtin_nontemporal_store(acc, (f4*)(parts + (size_t)sch * (BB * HH) + b * HH + c0));
}

// ---------------- K2: feats @ w1 -> hdn (atomics) + scatter-inv ------------
// grid = 265: blocks 0..255 = 16 w1-rows each; 256 = rows 4096..4097;
//             257..264 = scatter-inv.
__global__ void mlp1_kernel(const float* __restrict__ parts,
                            const float* __restrict__ w1,
                            const int* __restrict__ layer_idx,
                            const int* __restrict__ cache_position,
                            float* __restrict__ hdn,
                            int* __restrict__ inv) {
    const int blk = blockIdx.x, t = threadIdx.x;
    if (blk >= 257) {                      // scatter
        int i = (blk - 257) * 256 + t;
        int pos = cache_position[i];
        if (pos >= 0 && pos < SS) atomicMax(&inv[pos], i);  // last-wins
        return;
    }
    __shared__ float feats_s[16][4];
    const int k0 = blk * 16;
    const int kcnt = (blk < 256) ? 16 : 2;
    if (blk < 256) {
        // cooperative partial reduction: 64 (kk,b) pairs x 4 sub-threads
        // sub handles 32 of the 128 sch partials
        int kk = t >> 4, bb = (t >> 2) & 3, sub = t & 3;
        const float* src = parts + (size_t)(sub * 32) * (BB * HH) + bb * HH + (k0 + kk);
        float r = 0.f;
        #pragma unroll
        for (int u = 0; u < 32; ++u)
            r += src[(size_t)u * (BB * HH)];
        r += __shfl_xor(r, 1, 64);
        r += __shfl_xor(r, 2, 64);
        if (sub == 0) feats_s[kk][bb] = r * (1.0f / (float)SS);
        __syncthreads();
    }
    // GEMV: thread owns 4 consecutive j
    int j0 = t * 4;
    f4 acc[BB];
    #pragma unroll
    for (int b = 0; b < BB; ++b) acc[b] = (f4)(0.f);
    for (int kk = 0; kk < kcnt; ++kk) {
        int k = k0 + kk;
        f4 w = *(const f4*)(w1 + (size_t)k * HDN + j0);
        float f[BB];
        if (blk < 256) {
            #pragma unroll
            for (int b = 0; b < BB; ++b) f[b] = feats_s[kk][b];
        } else {
            float v = (kk == 0) ? (float)(*layer_idx) : (float)SS;
            #pragma unroll
            for (int b = 0; b < BB; ++b) f[b] = v;
        }
        #pragma unroll
        for (int b = 0; b < BB; ++b) acc[b] += f[b] * w;
    }
    #pragma unroll
    for (int b = 0; b < BB; ++b) {
        float* h = hdn + b * HDN + j0;
        atomicAdd(h + 0, acc[b].x);
        atomicAdd(h + 1, acc[b].y);
        atomicAdd(h + 2, acc[b].z);
        atomicAdd(h + 3, acc[b].w);
    }
}

// -------- K3: per-block 4-batch mlp2 prologue + 4x grid-stride output ------
// grid = 2048 blocks x 256 threads; 4 iterations; idx = it*2^19 + blk*256+t.
// Note idx>>19 == it, so batch b == it each iteration.
__global__ __launch_bounds__(256)
void out_kernel(const float* __restrict__ key,
                const float* __restrict__ value,
                const float* __restrict__ k_cache,
                const float* __restrict__ v_cache,
                const float* __restrict__ k_left,
                const float* __restrict__ v_left,
                const float* __restrict__ hdn,
                const float* __restrict__ b1,
                const float* __restrict__ w2,
                const float* __restrict__ b2,
                const int* __restrict__ inv,
                float* __restrict__ out) {
    const int blk = blockIdx.x, t = threadIdx.x;

    // --- prologue: mlp2 for ALL 4 batches (redundant per block) ---
    __shared__ float wred[4][16];
    __shared__ float logits[16];
    __shared__ float w0_s[BB], wl_s[BB];
    {
        int j0 = t * 4;
        float l[BB][4];
        #pragma unroll
        for (int b = 0; b < BB; ++b)
            #pragma unroll
            for (int m = 0; m < 4; ++m) l[b][m] = 0.f;
        #pragma unroll
        for (int jj = 0; jj < 4; ++jj) {
            int j = j0 + jj;
            float bias = b1[j];
            f4 w2v = *(const f4*)(w2 + j * 4);
            #pragma unroll
            for (int b = 0; b < BB; ++b) {
                float h = hdn[b * HDN + j] + bias;
                h = h > 0.f ? h : 0.f;
                l[b][0] = fmaf(h, w2v.x, l[b][0]);
                l[b][1] = fmaf(h, w2v.y, l[b][1]);
                l[b][2] = fmaf(h, w2v.z, l[b][2]);
                l[b][3] = fmaf(h, w2v.w, l[b][3]);
            }
        }
        int wave = t >> 6, lane = t & 63;
        #pragma unroll
        for (int off = 32; off > 0; off >>= 1)
            #pragma unroll
            for (int b = 0; b < BB; ++b)
                #pragma unroll
                for (int m = 0; m < 4; ++m)
                    l[b][m] += __shfl_down(l[b][m], off, 64);
        if (lane == 0)
            #pragma unroll
            for (int b = 0; b < BB; ++b)
                #pragma unroll
                for (int m = 0; m < 4; ++m)
                    wred[wave][b * 4 + m] = l[b][m];
        __syncthreads();
        if (t < 16) logits[t] = wred[0][t] + wred[1][t] + wred[2][t] + wred[3][t] + b2[t & 3];
        __syncthreads();
        if (t < BB) {
            float v0 = logits[t * 4 + 0], v1 = logits[t * 4 + 1];
            float v2 = logits[t * 4 + 2], v3 = logits[t * 4 + 3];
            float mx = fmaxf(fmaxf(v0, v1), fmaxf(v2, v3));
            float e0 = __expf(v0 - mx), e1 = __expf(v1 - mx);
            float e2 = __expf(v2 - mx), e3 = __expf(v3 - mx);
            float den = e0 + e1 + e2 + e3;
            w0_s[t] = e0 / den;
            wl_s[t] = e1 / den;
        }
        __syncthreads();
    }

    // --- main: 4 grid-stride iterations, one f4 of k_out + v_out each ---
    const int KV_OFF = BB * KVH * SS * (DD / 4);   // 2,097,152 f4
    f4* outv = (f4*)out;
    #pragma unroll
    for (int it = 0; it < 4; ++it) {
        int idx = it * (1 << 19) + blk * 256 + t;
        float w0 = w0_s[it];               // b == it
        float wl = wl_s[it];
        int d4 = idx & 31;
        int r  = idx >> 5;
        int s  = r & (SS - 1);
        int bh = r >> 11;
        int i = inv[s];
        bool hasLeft = d4 < (RANK / 4);
        f4 kd, vd, kl = (f4)(0.f), vl = (f4)(0.f);
        if (i >= 0) {
            size_t base = ((size_t)bh * SS + i) * DD;
            kd = *((const f4*)(key + base) + d4);
            vd = *((const f4*)(value + base) + d4);
            if (hasLeft) { kl = kd; vl = vd; }
        } else {
            size_t cbase = ((size_t)bh * MAXSEQ + s) * DD;
            kd = *((const f4*)(k_cache + cbase) + d4);
            vd = *((const f4*)(v_cache + cbase) + d4);
            if (hasLeft) {
                size_t lbase = ((size_t)bh * MAXSEQ + s) * RANK;
                kl = *((const f4*)(k_left + lbase) + d4);
                vl = *((const f4*)(v_left + lbase) + d4);
            }
        }
        f4 ko = w0 * kd + wl * kl;
        f4 vo = w0 * vd + wl * vl;
        __builtin_nontemporal_store(ko, outv + idx);
        __builtin_nontemporal_store(vo, outv + idx + KV_OFF);
    }
}

extern "C" void kernel_launch(void* const* d_in, const int* in_sizes, int n_in,
                              void* d_out, int out_size, void* d_ws, size_t ws_size,
                              hipStream_t stream) {
    const float* hidden   = (const float*)d_in[0];
    const float* key      = (const float*)d_in[1];
    const float* value    = (const float*)d_in[2];
    const float* k_cache  = (const float*)d_in[3];
    const float* v_cache  = (const float*)d_in[4];
    const float* k_left   = (const float*)d_in[5];
    const float* v_left   = (const float*)d_in[6];
    const float* w1       = (const float*)d_in[7];
    const float* b1       = (const float*)d_in[8];
    const float* w2       = (const float*)d_in[9];
    const float* b2       = (const float*)d_in[10];
    const int*   cachepos = (const int*)d_in[11];
    const int*   layeridx = (const int*)d_in[12];
    float* out = (float*)d_out;

    float* wsf   = (float*)d_ws;
    float* parts = wsf + WS_PARTS;
    float* hdn   = wsf + WS_HDN;
    int*   inv   = (int*)wsf + WS_INV;

    // K1: pool partials (nt stores) + inv=-1 + hdn=0
    pool_kernel<<<2048, 256, 0, stream>>>(hidden, parts, hdn, inv);
    // K2: reduce partials -> feats; GEMV w1 -> hdn; scatter-inv
    mlp1_kernel<<<265, 256, 0, stream>>>(parts, w1, layeridx, cachepos, hdn, inv);
    // K3: per-block 4-batch mlp2 + 4x grid-stride fused output (nt stores)
    out_kernel<<<2048, 256, 0, stream>>>(
        key, value, k_cache, v_cache, k_left, v_left,
        hdn, b1, w2, b2, inv, out);
}

// Round 11
// 85.423 us; speedup vs baseline: 5.5810x; 1.0174x over previous
//
#include <hip/hip_runtime.h>

// Problem constants (fixed by setup_inputs)
#define BB 4
#define SS 2048
#define HH 4096
#define KVH 8
#define DD 128
#define MAXSEQ 4096
#define RANK 64
#define HDN 1024   // H/4
#define NSCH 128   // s-chunks for pool partials (16 rows each)

typedef float f4 __attribute__((ext_vector_type(4)));

// Workspace layout (float slots):
//   [0, 2097152)            parts[sch][b][c]  (128 * 4 * 4096)
//   [2097152, 2101248)      hdn (B*HDN)
//   ints at [2101248, 2103296): inv[SS]
#define WS_PARTS 0
#define WS_HDN   2097152
#define WS_INV   2101248

// ---------------- K1: pool partials (no atomics) + ws init duties ----------
// grid = 2048 blocks x 256. Block: b(4) x sch(128) x cblk(4); 16 rows x 1024 ch.
__global__ void pool_kernel(const float* __restrict__ hidden,
                            float* __restrict__ parts,
                            float* __restrict__ hdn,
                            int* __restrict__ inv) {
    const int blk = blockIdx.x, t = threadIdx.x;
    // side duties (these blocks also do pool work below)
    if (blk >= 2040) {                     // 8 blocks: inv = -1
        inv[(blk - 2040) * 256 + t] = -1;
    } else if (blk >= 2038) {              // 2 blocks: hdn = 0 (4096 floats)
        int i = (blk - 2038) * 256 + t;
        #pragma unroll
        for (int u = 0; u < 8; ++u) hdn[i * 8 + u] = 0.0f;
    }
    int b    = blk >> 9;
    int sch  = (blk >> 2) & 127;
    int cblk = blk & 3;
    int c0 = cblk * 1024 + t * 4;
    const float* base = hidden + (size_t)b * SS * HH + (size_t)sch * 16 * HH + c0;
    f4 acc = (f4)(0.f);
    #pragma unroll
    for (int s = 0; s < 16; ++s)
        acc += *(const f4*)(base + (size_t)s * HH);
    // parts[sch][b][c0..c0+3] — plain store: K2 re-reads this immediately (L2)
    *(f4*)(parts + (size_t)sch * (BB * HH) + b * HH + c0) = acc;
}

// ---------------- K2: feats @ w1 -> hdn (atomics) + scatter-inv ------------
// grid = 265: blocks 0..255 = 16 w1-rows each; 256 = rows 4096..4097;
//             257..264 = scatter-inv.
__global__ void mlp1_kernel(const float* __restrict__ parts,
                            const float* __restrict__ w1,
                            const int* __restrict__ layer_idx,
                            const int* __restrict__ cache_position,
                            float* __restrict__ hdn,
                            int* __restrict__ inv) {
    const int blk = blockIdx.x, t = threadIdx.x;
    if (blk >= 257) {                      // scatter
        int i = (blk - 257) * 256 + t;
        int pos = cache_position[i];
        if (pos >= 0 && pos < SS) atomicMax(&inv[pos], i);  // last-wins
        return;
    }
    __shared__ float feats_s[16][4];
    const int k0 = blk * 16;
    const int kcnt = (blk < 256) ? 16 : 2;
    if (blk < 256) {
        // Coalesced partial reduction over 128 sch.
        // lane layout: kf4 = t&3 (f4 within 16 k's), bb = (t>>2)&3, sg = t>>4.
        // 4 consecutive lanes read one contiguous 64B line.
        int kf4 = t & 3, bb = (t >> 2) & 3, sg = t >> 4;
        f4 a = (f4)(0.f);
        #pragma unroll
        for (int u = 0; u < 8; ++u) {
            int sch = sg + 16 * u;
            a += *(const f4*)(parts + (size_t)sch * (BB * HH) + bb * HH + k0 + kf4 * 4);
        }
        // sum over the wave's 4 sg values (lanes l, l^16, l^32 share (kf4,bb))
        #pragma unroll
        for (int m = 0; m < 4; ++m) {
            a[m] += __shfl_xor(a[m], 16, 64);
            a[m] += __shfl_xor(a[m], 32, 64);
        }
        __shared__ f4 red[4][16];
        if ((t & 63) < 16) red[t >> 6][t & 15] = a;
        __syncthreads();
        if (t < 16) {
            f4 s = red[0][t] + red[1][t] + red[2][t] + red[3][t];
            s *= (1.0f / (float)SS);
            int kf = t & 3, b = t >> 2;
            feats_s[kf * 4 + 0][b] = s.x;
            feats_s[kf * 4 + 1][b] = s.y;
            feats_s[kf * 4 + 2][b] = s.z;
            feats_s[kf * 4 + 3][b] = s.w;
        }
        __syncthreads();
    }
    // GEMV: thread owns 4 consecutive j
    int j0 = t * 4;
    f4 acc[BB];
    #pragma unroll
    for (int b = 0; b < BB; ++b) acc[b] = (f4)(0.f);
    for (int kk = 0; kk < kcnt; ++kk) {
        int k = k0 + kk;
        f4 w = *(const f4*)(w1 + (size_t)k * HDN + j0);
        float f[BB];
        if (blk < 256) {
            #pragma unroll
            for (int b = 0; b < BB; ++b) f[b] = feats_s[kk][b];
        } else {
            float v = (kk == 0) ? (float)(*layer_idx) : (float)SS;
            #pragma unroll
            for (int b = 0; b < BB; ++b) f[b] = v;
        }
        #pragma unroll
        for (int b = 0; b < BB; ++b) acc[b] += f[b] * w;
    }
    #pragma unroll
    for (int b = 0; b < BB; ++b) {
        float* h = hdn + b * HDN + j0;
        atomicAdd(h + 0, acc[b].x);
        atomicAdd(h + 1, acc[b].y);
        atomicAdd(h + 2, acc[b].z);
        atomicAdd(h + 3, acc[b].w);
    }
}

// -------- K3: per-block 4-batch mlp2 prologue + 4x grid-stride output ------
// grid = 2048 blocks x 256 threads; 4 iterations; idx = it*2^19 + blk*256+t.
// Note idx>>19 == it, so batch b == it each iteration.
__global__ __launch_bounds__(256)
void out_kernel(const float* __restrict__ key,
                const float* __restrict__ value,
                const float* __restrict__ k_cache,
                const float* __restrict__ v_cache,
                const float* __restrict__ k_left,
                const float* __restrict__ v_left,
                const float* __restrict__ hdn,
                const float* __restrict__ b1,
                const float* __restrict__ w2,
                const float* __restrict__ b2,
                const int* __restrict__ inv,
                float* __restrict__ out) {
    const int blk = blockIdx.x, t = threadIdx.x;

    // --- prologue: mlp2 for ALL 4 batches (redundant per block) ---
    __shared__ float wred[4][16];
    __shared__ float logits[16];
    __shared__ float w0_s[BB], wl_s[BB];
    {
        int j0 = t * 4;
        float l[BB][4];
        #pragma unroll
        for (int b = 0; b < BB; ++b)
            #pragma unroll
            for (int m = 0; m < 4; ++m) l[b][m] = 0.f;
        #pragma unroll
        for (int jj = 0; jj < 4; ++jj) {
            int j = j0 + jj;
            float bias = b1[j];
            f4 w2v = *(const f4*)(w2 + j * 4);
            #pragma unroll
            for (int b = 0; b < BB; ++b) {
                float h = hdn[b * HDN + j] + bias;
                h = h > 0.f ? h : 0.f;
                l[b][0] = fmaf(h, w2v.x, l[b][0]);
                l[b][1] = fmaf(h, w2v.y, l[b][1]);
                l[b][2] = fmaf(h, w2v.z, l[b][2]);
                l[b][3] = fmaf(h, w2v.w, l[b][3]);
            }
        }
        int wave = t >> 6, lane = t & 63;
        #pragma unroll
        for (int off = 32; off > 0; off >>= 1)
            #pragma unroll
            for (int b = 0; b < BB; ++b)
                #pragma unroll
                for (int m = 0; m < 4; ++m)
                    l[b][m] += __shfl_down(l[b][m], off, 64);
        if (lane == 0)
            #pragma unroll
            for (int b = 0; b < BB; ++b)
                #pragma unroll
                for (int m = 0; m < 4; ++m)
                    wred[wave][b * 4 + m] = l[b][m];
        __syncthreads();
        if (t < 16) logits[t] = wred[0][t] + wred[1][t] + wred[2][t] + wred[3][t] + b2[t & 3];
        __syncthreads();
        if (t < BB) {
            float v0 = logits[t * 4 + 0], v1 = logits[t * 4 + 1];
            float v2 = logits[t * 4 + 2], v3 = logits[t * 4 + 3];
            float mx = fmaxf(fmaxf(v0, v1), fmaxf(v2, v3));
            float e0 = __expf(v0 - mx), e1 = __expf(v1 - mx);
            float e2 = __expf(v2 - mx), e3 = __expf(v3 - mx);
            float den = e0 + e1 + e2 + e3;
            w0_s[t] = e0 / den;
            wl_s[t] = e1 / den;
        }
        __syncthreads();
    }

    // --- main: 4 grid-stride iterations, one f4 of k_out + v_out each ---
    const int KV_OFF = BB * KVH * SS * (DD / 4);   // 2,097,152 f4
    f4* outv = (f4*)out;
    #pragma unroll
    for (int it = 0; it < 4; ++it) {
        int idx = it * (1 << 19) + blk * 256 + t;
        float w0 = w0_s[it];               // b == it
        float wl = wl_s[it];
        int d4 = idx & 31;
        int r  = idx >> 5;
        int s  = r & (SS - 1);
        int bh = r >> 11;
        int i = inv[s];
        bool hasLeft = d4 < (RANK / 4);
        f4 kd, vd, kl = (f4)(0.f), vl = (f4)(0.f);
        if (i >= 0) {
            size_t base = ((size_t)bh * SS + i) * DD;
            kd = *((const f4*)(key + base) + d4);
            vd = *((const f4*)(value + base) + d4);
            if (hasLeft) { kl = kd; vl = vd; }
        } else {
            size_t cbase = ((size_t)bh * MAXSEQ + s) * DD;
            kd = *((const f4*)(k_cache + cbase) + d4);
            vd = *((const f4*)(v_cache + cbase) + d4);
            if (hasLeft) {
                size_t lbase = ((size_t)bh * MAXSEQ + s) * RANK;
                kl = *((const f4*)(k_left + lbase) + d4);
                vl = *((const f4*)(v_left + lbase) + d4);
            }
        }
        f4 ko = w0 * kd + wl * kl;
        f4 vo = w0 * vd + wl * vl;
        __builtin_nontemporal_store(ko, outv + idx);
        __builtin_nontemporal_store(vo, outv + idx + KV_OFF);
    }
}

extern "C" void kernel_launch(void* const* d_in, const int* in_sizes, int n_in,
                              void* d_out, int out_size, void* d_ws, size_t ws_size,
                              hipStream_t stream) {
    const float* hidden   = (const float*)d_in[0];
    const float* key      = (const float*)d_in[1];
    const float* value    = (const float*)d_in[2];
    const float* k_cache  = (const float*)d_in[3];
    const float* v_cache  = (const float*)d_in[4];
    const float* k_left   = (const float*)d_in[5];
    const float* v_left   = (const float*)d_in[6];
    const float* w1       = (const float*)d_in[7];
    const float* b1       = (const float*)d_in[8];
    const float* w2       = (const float*)d_in[9];
    const float* b2       = (const float*)d_in[10];
    const int*   cachepos = (const int*)d_in[11];
    const int*   layeridx = (const int*)d_in[12];
    float* out = (float*)d_out;

    float* wsf   = (float*)d_ws;
    float* parts = wsf + WS_PARTS;
    float* hdn   = wsf + WS_HDN;
    int*   inv   = (int*)wsf + WS_INV;

    // K1: pool partials + inv=-1 + hdn=0
    pool_kernel<<<2048, 256, 0, stream>>>(hidden, parts, hdn, inv);
    // K2: coalesced reduce -> feats; GEMV w1 -> hdn; scatter-inv
    mlp1_kernel<<<265, 256, 0, stream>>>(parts, w1, layeridx, cachepos, hdn, inv);
    // K3: per-block 4-batch mlp2 + 4x grid-stride fused output (nt stores)
    out_kernel<<<2048, 256, 0, stream>>>(
        key, value, k_cache, v_cache, k_left, v_left,
        hdn, b1, w2, b2, inv, out);
}